// Round 3
// baseline (453.092 us; speedup 1.0000x reference)
//
#include <hip/hip_runtime.h>
#include <hip/hip_bf16.h>

#define B_  8
#define N_  131072
#define C_  64
#define SD_ 256

typedef __attribute__((ext_vector_type(8))) short  short8;   // 8 bf16 (4 VGPRs)
typedef __attribute__((ext_vector_type(4))) float  floatx4;  // MFMA C/D frag

static __device__ inline short bf16_of(float f) {
    __hip_bfloat16 h = __float2bfloat16(f);
    return *reinterpret_cast<short*>(&h);
}

// ---------------------------------------------------------------------------
// Kernel 1: per-batch modulated + demodulated weight -> bf16, layout (b, o, i)
// One block per batch, 256 threads. Tiny (runs in a few microseconds).
// ---------------------------------------------------------------------------
__global__ void modw_kernel(const float* __restrict__ style,
                            const float* __restrict__ weight,
                            const float* __restrict__ mod_weight,
                            const float* __restrict__ mod_bias,
                            __hip_bfloat16* __restrict__ wout) {
    const int b = blockIdx.x;
    const int t = threadIdx.x;          // 256
    __shared__ float part[4][64];
    __shared__ float s_sh[64];

    // s[i] = (1/sqrt(256)) * sum_d style[b][d]*mod_weight[i][d] + mod_bias[i] + 1
    const int i   = t & 63;
    const int seg = t >> 6;             // 4 segments of 64 d-values
    {
        const float* st = style + b * SD_ + seg * 64;
        const float* mw = mod_weight + i * SD_ + seg * 64;
        float p = 0.f;
        #pragma unroll
        for (int d = 0; d < 64; ++d) p += st[d] * mw[d];
        part[seg][i] = p;
    }
    __syncthreads();
    if (t < 64) {
        float s = (part[0][t] + part[1][t] + part[2][t] + part[3][t]) * 0.0625f
                  + mod_bias[t] + 1.0f;
        s_sh[t] = s;
    }
    __syncthreads();
    if (t < 64) {
        const int o = t;
        float wt[64];
        float sumsq = 0.f;
        #pragma unroll
        for (int ii = 0; ii < 64; ++ii) {
            float v = 0.125f * weight[o * 64 + ii] * s_sh[ii];  // scale=1/sqrt(64)
            wt[ii] = v;
            sumsq += v * v;
        }
        const float demod = rsqrtf(sumsq + 1e-8f);
        #pragma unroll
        for (int ii = 0; ii < 64; ++ii)
            wout[(b * 64 + o) * 64 + ii] = __float2bfloat16(wt[ii] * demod);
    }
}

// ---------------------------------------------------------------------------
// Kernel 2: out[b] = x[b] @ w[b]^T + bias, streamed via bf16 MFMA.
// One wave = 64 points (4 MFMA point-tiles of 16), all 64 outputs.
//
// Round-3 change vs round-2: depth-2 software pipeline instead of hoisting
// all 16 loads.  Two named tile buffers (A/B, static indexing only); tile
// pt+2 is prefetched into the buffer just consumed, before the MFMA+store
// of tile pt.  Per-wave in-flight loads drop 16->8, VGPR drops ~150->~110,
// so __launch_bounds__(256,4) doubles occupancy to 4 waves/SIMD while
// aggregate in-flight bytes per CU stay the same.  Stores stay regular
// (L2-merged); operand order stays swapped (D[m=out_ch][n=point]).
// ---------------------------------------------------------------------------
#define LOADT(buf, pt)                                                     \
    do {                                                                   \
        const float* xr_ = xb + ((pt) * 16 + row) * C_ + quad * 8;         \
        buf##0 = *(const floatx4*)(xr_);                                   \
        buf##1 = *(const floatx4*)(xr_ + 4);                               \
        buf##2 = *(const floatx4*)(xr_ + 32);                              \
        buf##3 = *(const floatx4*)(xr_ + 36);                              \
    } while (0)

#define CVT(buf, xf0, xf1)                                                 \
    do {                                                                   \
        _Pragma("unroll")                                                  \
        for (int j = 0; j < 4; ++j) {                                      \
            xf0[j]     = bf16_of(buf##0[j]);                               \
            xf0[j + 4] = bf16_of(buf##1[j]);                               \
            xf1[j]     = bf16_of(buf##2[j]);                               \
            xf1[j + 4] = bf16_of(buf##3[j]);                               \
        }                                                                  \
    } while (0)

#define MFMA_STORE(pt, xf0, xf1)                                           \
    do {                                                                   \
        floatx4 acc0 = bias_v0, acc1 = bias_v1, acc2 = bias_v2, acc3 = bias_v3; \
        acc0 = __builtin_amdgcn_mfma_f32_16x16x32_bf16(wf00, xf0, acc0, 0, 0, 0); \
        acc0 = __builtin_amdgcn_mfma_f32_16x16x32_bf16(wf01, xf1, acc0, 0, 0, 0); \
        acc1 = __builtin_amdgcn_mfma_f32_16x16x32_bf16(wf10, xf0, acc1, 0, 0, 0); \
        acc1 = __builtin_amdgcn_mfma_f32_16x16x32_bf16(wf11, xf1, acc1, 0, 0, 0); \
        acc2 = __builtin_amdgcn_mfma_f32_16x16x32_bf16(wf20, xf0, acc2, 0, 0, 0); \
        acc2 = __builtin_amdgcn_mfma_f32_16x16x32_bf16(wf21, xf1, acc2, 0, 0, 0); \
        acc3 = __builtin_amdgcn_mfma_f32_16x16x32_bf16(wf30, xf0, acc3, 0, 0, 0); \
        acc3 = __builtin_amdgcn_mfma_f32_16x16x32_bf16(wf31, xf1, acc3, 0, 0, 0); \
        float* orow_ = ob + ((pt) * 16 + row) * C_ + quad * 4;             \
        *(floatx4*)(orow_ +  0) = acc0;                                    \
        *(floatx4*)(orow_ + 16) = acc1;                                    \
        *(floatx4*)(orow_ + 32) = acc2;                                    \
        *(floatx4*)(orow_ + 48) = acc3;                                    \
    } while (0)

__global__ __launch_bounds__(256, 4) void conv_kernel(
        const float* __restrict__ x,
        const __hip_bfloat16* __restrict__ wmod,
        const float* __restrict__ bias,
        float* __restrict__ out) {
    const int lane = threadIdx.x & 63;
    const int wid  = threadIdx.x >> 6;
    const int gw   = blockIdx.x * 4 + wid;   // 0..16383
    const int b    = gw >> 11;               // 2048 waves / batch
    const int p0   = (gw & 2047) * 64;       // first point of this wave
    const int row  = lane & 15;              // A.m (out-ch) / B.n (point) index
    const int quad = lane >> 4;              // k-quad / D.row-quad

    const size_t base = ((size_t)b * N_ + p0) * C_;
    const float* xb = x + base;
    float*       ob = out + base;

    // --- depth-2 pipeline buffers (named, static indexing only)
    floatx4 A0, A1, A2, A3, B0, B1, B2, B3;
    LOADT(A, 0);                     // tile 0 in flight
    LOADT(B, 1);                     // tile 1 in flight

    // --- W fragments: w[o = mt*16+row][k = ks*32 + quad*8 ..+8], bf16, L2-resident
    const short* wb = (const short*)(wmod) + b * 64 * 64;
    short8 wf00 = *(const short8*)(wb + ( 0 + row) * 64 +  0 + quad * 8);
    short8 wf01 = *(const short8*)(wb + ( 0 + row) * 64 + 32 + quad * 8);
    short8 wf10 = *(const short8*)(wb + (16 + row) * 64 +  0 + quad * 8);
    short8 wf11 = *(const short8*)(wb + (16 + row) * 64 + 32 + quad * 8);
    short8 wf20 = *(const short8*)(wb + (32 + row) * 64 +  0 + quad * 8);
    short8 wf21 = *(const short8*)(wb + (32 + row) * 64 + 32 + quad * 8);
    short8 wf30 = *(const short8*)(wb + (48 + row) * 64 +  0 + quad * 8);
    short8 wf31 = *(const short8*)(wb + (48 + row) * 64 + 32 + quad * 8);

    // --- bias (zeros here, but reference adds it); D row m = quad*4+r
    floatx4 bias_v0 = *(const floatx4*)(bias +  0 + quad * 4);
    floatx4 bias_v1 = *(const floatx4*)(bias + 16 + quad * 4);
    floatx4 bias_v2 = *(const floatx4*)(bias + 32 + quad * 4);
    floatx4 bias_v3 = *(const floatx4*)(bias + 48 + quad * 4);

    short8 xf0, xf1;

    // tile 0: consume A, then refill A with tile 2
    CVT(A, xf0, xf1);
    LOADT(A, 2);
    MFMA_STORE(0, xf0, xf1);

    // tile 1: consume B, then refill B with tile 3
    CVT(B, xf0, xf1);
    LOADT(B, 3);
    MFMA_STORE(1, xf0, xf1);

    // tile 2
    CVT(A, xf0, xf1);
    MFMA_STORE(2, xf0, xf1);

    // tile 3
    CVT(B, xf0, xf1);
    MFMA_STORE(3, xf0, xf1);
}

extern "C" void kernel_launch(void* const* d_in, const int* in_sizes, int n_in,
                              void* d_out, int out_size, void* d_ws, size_t ws_size,
                              hipStream_t stream) {
    const float* x          = (const float*)d_in[0];
    const float* style      = (const float*)d_in[1];
    const float* weight     = (const float*)d_in[2];
    const float* bias       = (const float*)d_in[3];
    const float* mod_weight = (const float*)d_in[4];
    const float* mod_bias   = (const float*)d_in[5];
    float* out = (float*)d_out;
    __hip_bfloat16* wmod = (__hip_bfloat16*)d_ws;   // 8*64*64*2 = 64 KB

    modw_kernel<<<dim3(B_), dim3(256), 0, stream>>>(style, weight, mod_weight, mod_bias, wmod);
    conv_kernel<<<dim3((B_ * N_) / 256), dim3(256), 0, stream>>>(x, wmod, bias, out);
}

// Round 4
// 440.383 us; speedup vs baseline: 1.0289x; 1.0289x over previous
//
#include <hip/hip_runtime.h>
#include <hip/hip_bf16.h>

#define B_  8
#define N_  131072
#define C_  64
#define SD_ 256

typedef __attribute__((ext_vector_type(8))) short  short8;   // 8 bf16 (4 VGPRs)
typedef __attribute__((ext_vector_type(4))) float  floatx4;  // MFMA C/D frag

typedef const __attribute__((address_space(1))) void  cglb_t; // global src for GLL
typedef       __attribute__((address_space(3))) void  lds_t;  // LDS dst for GLL

static __device__ inline short bf16_of(float f) {
    __hip_bfloat16 h = __float2bfloat16(f);
    return *reinterpret_cast<short*>(&h);
}

// ---------------------------------------------------------------------------
// Kernel 1: per-batch modulated + demodulated weight -> bf16, layout (b, o, i)
// One block per batch, 256 threads. Tiny (runs in a few microseconds).
// ---------------------------------------------------------------------------
__global__ void modw_kernel(const float* __restrict__ style,
                            const float* __restrict__ weight,
                            const float* __restrict__ mod_weight,
                            const float* __restrict__ mod_bias,
                            __hip_bfloat16* __restrict__ wout) {
    const int b = blockIdx.x;
    const int t = threadIdx.x;          // 256
    __shared__ float part[4][64];
    __shared__ float s_sh[64];

    // s[i] = (1/sqrt(256)) * sum_d style[b][d]*mod_weight[i][d] + mod_bias[i] + 1
    const int i   = t & 63;
    const int seg = t >> 6;             // 4 segments of 64 d-values
    {
        const float* st = style + b * SD_ + seg * 64;
        const float* mw = mod_weight + i * SD_ + seg * 64;
        float p = 0.f;
        #pragma unroll
        for (int d = 0; d < 64; ++d) p += st[d] * mw[d];
        part[seg][i] = p;
    }
    __syncthreads();
    if (t < 64) {
        float s = (part[0][t] + part[1][t] + part[2][t] + part[3][t]) * 0.0625f
                  + mod_bias[t] + 1.0f;
        s_sh[t] = s;
    }
    __syncthreads();
    if (t < 64) {
        const int o = t;
        float wt[64];
        float sumsq = 0.f;
        #pragma unroll
        for (int ii = 0; ii < 64; ++ii) {
            float v = 0.125f * weight[o * 64 + ii] * s_sh[ii];  // scale=1/sqrt(64)
            wt[ii] = v;
            sumsq += v * v;
        }
        const float demod = rsqrtf(sumsq + 1e-8f);
        #pragma unroll
        for (int ii = 0; ii < 64; ++ii)
            wout[(b * 64 + o) * 64 + ii] = __float2bfloat16(wt[ii] * demod);
    }
}

// ---------------------------------------------------------------------------
// Kernel 2: out[b] = x[b] @ w[b]^T + bias, streamed via bf16 MFMA.
// One wave = 64 points (4 MFMA point-tiles of 16), all 64 outputs.
//
// Round-4 change: make the GLOBAL access pattern copy-identical (linear,
// 128B-granular on both streams) and do ALL fragment scatter through LDS.
//  * Input: each wave stages its full 16 KB via global_load_lds (linear
//    lane-contiguous global reads, no VGPR round trip), one vmcnt(0) drain
//    (per-wave staging -> zero barriers), fragments come from ds_read.
//  * Output: MFMA acc fragments are ds_written into the just-consumed LDS
//    tile region, read back linearly, stored as lane-contiguous dwordx4
//    (the same pattern the 6.4 TB/s harness fills use).
//  * Every prior variant (rounds 0-3) shared the fragment-scattered global
//    pattern (16 cache lines @ 64B-used per load instr, 16 half-lines per
//    store instr = 2x minimum L2 request count) — this is the one axis not
//    yet tested.  LDS traffic is ~2x537 MB at 69 TB/s aggregate = free.
// ---------------------------------------------------------------------------
__global__ __launch_bounds__(256, 4) void conv_kernel(
        const float* __restrict__ x,
        const __hip_bfloat16* __restrict__ wmod,
        const float* __restrict__ bias,
        float* __restrict__ out) {
    const int lane = threadIdx.x & 63;
    const int wid  = threadIdx.x >> 6;
    const int gw   = blockIdx.x * 4 + wid;   // 0..16383
    const int b    = gw >> 11;               // 2048 waves / batch
    const int p0   = (gw & 2047) * 64;       // first point of this wave
    const int row  = lane & 15;              // point index within a 16-tile
    const int quad = lane >> 4;              // k-quad / D.row-quad

    __shared__ __align__(16) float smem[4 * 4096];   // 16 KB per wave
    float* ws = smem + wid * 4096;

    const size_t base = ((size_t)b * N_ + p0) * C_;
    const float* xb = x + base;
    float*       ob = out + base;

    // --- Stage all 4 tiles (64 rows x 64 ch = 16 KB) linearly into LDS.
    // Global src is lane-contiguous (lane*16B); LDS dst is uniform base
    // (+ HW lane*16B) -> linear layout, matching the global layout exactly.
    #pragma unroll
    for (int t = 0; t < 4; ++t)
        #pragma unroll
        for (int c = 0; c < 4; ++c)
            __builtin_amdgcn_global_load_lds(
                (cglb_t*)(xb + t * 1024 + c * 256 + lane * 4),
                (lds_t*)(ws + t * 1024 + c * 256),
                16, 0, 0);

    // --- W fragments (L2-resident) + bias, overlapping the GLL latency.
    const short* wb = (const short*)(wmod) + b * 64 * 64;
    short8 wf00 = *(const short8*)(wb + ( 0 + row) * 64 +  0 + quad * 8);
    short8 wf01 = *(const short8*)(wb + ( 0 + row) * 64 + 32 + quad * 8);
    short8 wf10 = *(const short8*)(wb + (16 + row) * 64 +  0 + quad * 8);
    short8 wf11 = *(const short8*)(wb + (16 + row) * 64 + 32 + quad * 8);
    short8 wf20 = *(const short8*)(wb + (32 + row) * 64 +  0 + quad * 8);
    short8 wf21 = *(const short8*)(wb + (32 + row) * 64 + 32 + quad * 8);
    short8 wf30 = *(const short8*)(wb + (48 + row) * 64 +  0 + quad * 8);
    short8 wf31 = *(const short8*)(wb + (48 + row) * 64 + 32 + quad * 8);

    floatx4 bias_v0 = *(const floatx4*)(bias +  0 + quad * 4);
    floatx4 bias_v1 = *(const floatx4*)(bias + 16 + quad * 4);
    floatx4 bias_v2 = *(const floatx4*)(bias + 32 + quad * 4);
    floatx4 bias_v3 = *(const floatx4*)(bias + 48 + quad * 4);

    // Drain staging (and wf/bias) — per-wave, no barrier needed.  The
    // "memory" clobber orders all following ds_reads after this point.
    asm volatile("s_waitcnt vmcnt(0)" ::: "memory");

    #pragma unroll
    for (int t = 0; t < 4; ++t) {
        float* wt = ws + t * 1024;

        // --- fragments from LDS: x[p=t*16+row][k = quad*8..+8, 32+quad*8..+8]
        const float* fr = wt + row * 64 + quad * 8;
        floatx4 a0 = *(const floatx4*)(fr);
        floatx4 a1 = *(const floatx4*)(fr + 4);
        floatx4 a2 = *(const floatx4*)(fr + 32);
        floatx4 a3 = *(const floatx4*)(fr + 36);

        short8 xf0, xf1;
        #pragma unroll
        for (int j = 0; j < 4; ++j) {
            xf0[j]     = bf16_of(a0[j]);
            xf0[j + 4] = bf16_of(a1[j]);
            xf1[j]     = bf16_of(a2[j]);
            xf1[j + 4] = bf16_of(a3[j]);
        }

        floatx4 acc0 = bias_v0, acc1 = bias_v1, acc2 = bias_v2, acc3 = bias_v3;
        acc0 = __builtin_amdgcn_mfma_f32_16x16x32_bf16(wf00, xf0, acc0, 0, 0, 0);
        acc0 = __builtin_amdgcn_mfma_f32_16x16x32_bf16(wf01, xf1, acc0, 0, 0, 0);
        acc1 = __builtin_amdgcn_mfma_f32_16x16x32_bf16(wf10, xf0, acc1, 0, 0, 0);
        acc1 = __builtin_amdgcn_mfma_f32_16x16x32_bf16(wf11, xf1, acc1, 0, 0, 0);
        acc2 = __builtin_amdgcn_mfma_f32_16x16x32_bf16(wf20, xf0, acc2, 0, 0, 0);
        acc2 = __builtin_amdgcn_mfma_f32_16x16x32_bf16(wf21, xf1, acc2, 0, 0, 0);
        acc3 = __builtin_amdgcn_mfma_f32_16x16x32_bf16(wf30, xf0, acc3, 0, 0, 0);
        acc3 = __builtin_amdgcn_mfma_f32_16x16x32_bf16(wf31, xf1, acc3, 0, 0, 0);

        // --- out-stage: scatter fragments into the consumed tile region.
        // D[m=out_ch][n=point]: lane holds channels mt*16+quad*4..+4 of
        // point (t*16+row) -> float idx row*64 + mt*16 + quad*4.
        float* wo = wt + row * 64 + quad * 4;
        *(floatx4*)(wo +  0) = acc0;
        *(floatx4*)(wo + 16) = acc1;
        *(floatx4*)(wo + 32) = acc2;
        *(floatx4*)(wo + 48) = acc3;

        // --- linear read-back + lane-contiguous global store (copy pattern)
        float* obt = ob + t * 1024;
        #pragma unroll
        for (int c = 0; c < 4; ++c) {
            floatx4 v = *(const floatx4*)(wt + c * 256 + lane * 4);
            *(floatx4*)(obt + c * 256 + lane * 4) = v;
        }
    }
}

extern "C" void kernel_launch(void* const* d_in, const int* in_sizes, int n_in,
                              void* d_out, int out_size, void* d_ws, size_t ws_size,
                              hipStream_t stream) {
    const float* x          = (const float*)d_in[0];
    const float* style      = (const float*)d_in[1];
    const float* weight     = (const float*)d_in[2];
    const float* bias       = (const float*)d_in[3];
    const float* mod_weight = (const float*)d_in[4];
    const float* mod_bias   = (const float*)d_in[5];
    float* out = (float*)d_out;
    __hip_bfloat16* wmod = (__hip_bfloat16*)d_ws;   // 8*64*64*2 = 64 KB

    modw_kernel<<<dim3(B_), dim3(256), 0, stream>>>(style, weight, mod_weight, mod_bias, wmod);
    conv_kernel<<<dim3((B_ * N_) / 256), dim3(256), 0, stream>>>(x, wmod, bias, out);
}

// Round 6
// 437.385 us; speedup vs baseline: 1.0359x; 1.0069x over previous
//
#include <hip/hip_runtime.h>
#include <hip/hip_bf16.h>

#define B_  8
#define N_  131072
#define C_  64
#define SD_ 256

typedef __attribute__((ext_vector_type(8))) short  short8;   // 8 bf16 (4 VGPRs)
typedef __attribute__((ext_vector_type(4))) float  floatx4;  // MFMA C/D frag

typedef const __attribute__((address_space(1))) void  cglb_t; // global src for GLL
typedef       __attribute__((address_space(3))) void  lds_t;  // LDS dst for GLL

static __device__ inline short bf16_of(float f) {
    __hip_bfloat16 h = __float2bfloat16(f);
    return *reinterpret_cast<short*>(&h);
}

// ---------------------------------------------------------------------------
// Kernel 1: per-batch modulated + demodulated weight -> bf16, layout (b, o, i)
// One block per batch, 256 threads. Tiny (runs in a few microseconds).
// ---------------------------------------------------------------------------
__global__ void modw_kernel(const float* __restrict__ style,
                            const float* __restrict__ weight,
                            const float* __restrict__ mod_weight,
                            const float* __restrict__ mod_bias,
                            __hip_bfloat16* __restrict__ wout) {
    const int b = blockIdx.x;
    const int t = threadIdx.x;          // 256
    __shared__ float part[4][64];
    __shared__ float s_sh[64];

    // s[i] = (1/sqrt(256)) * sum_d style[b][d]*mod_weight[i][d] + mod_bias[i] + 1
    const int i   = t & 63;
    const int seg = t >> 6;             // 4 segments of 64 d-values
    {
        const float* st = style + b * SD_ + seg * 64;
        const float* mw = mod_weight + i * SD_ + seg * 64;
        float p = 0.f;
        #pragma unroll
        for (int d = 0; d < 64; ++d) p += st[d] * mw[d];
        part[seg][i] = p;
    }
    __syncthreads();
    if (t < 64) {
        float s = (part[0][t] + part[1][t] + part[2][t] + part[3][t]) * 0.0625f
                  + mod_bias[t] + 1.0f;
        s_sh[t] = s;
    }
    __syncthreads();
    if (t < 64) {
        const int o = t;
        float wt[64];
        float sumsq = 0.f;
        #pragma unroll
        for (int ii = 0; ii < 64; ++ii) {
            float v = 0.125f * weight[o * 64 + ii] * s_sh[ii];  // scale=1/sqrt(64)
            wt[ii] = v;
            sumsq += v * v;
        }
        const float demod = rsqrtf(sumsq + 1e-8f);
        #pragma unroll
        for (int ii = 0; ii < 64; ++ii)
            wout[(b * 64 + o) * 64 + ii] = __float2bfloat16(wt[ii] * demod);
    }
}

// ---------------------------------------------------------------------------
// Kernel 2: out[b] = x[b] @ w[b]^T + bias, streamed via bf16 MFMA.
//
// Round-6: EXACT round-4 semantics (the verified 440us structure: each LDS
// byte gets one async GLL write -> fragment ds_reads -> one ordered
// ds-scatter of acc -> one linear ds_read; NO slot reuse, NO barriers),
// but the per-wave workload is halved to capture round-5's intended
// occupancy win safely:
//  * wave = 2 tiles (32 points, 8 KB LDS) instead of 4 tiles / 16 KB;
//    grid doubles to 8192 blocks.
//  * LDS/block 64KB -> 32KB  =>  4 blocks/CU (VGPR<=128 via (256,4))
//    => 16 waves/CU, 2x round 4.  Same per-wave drain/compute ratio, but
//    twice the TLP to cover the one vmcnt(0) stage-drain.
//  * Round-5 POST-MORTEM (why it corrupted): in-wave LDS slot reuse has a
//    WAR hazard — GLL's LDS write lands asynchronously at data-return
//    (vmcnt domain) and can beat still-queued ds ops (lgkmcnt domain) on
//    the same region; the compiler's partial lgkmcnt waits make the
//    window real.  This version has zero LDS reuse, so the hazard class
//    is structurally absent.
// ---------------------------------------------------------------------------
__global__ __launch_bounds__(256, 4) void conv_kernel(
        const float* __restrict__ x,
        const __hip_bfloat16* __restrict__ wmod,
        const float* __restrict__ bias,
        float* __restrict__ out) {
    const int lane = threadIdx.x & 63;
    const int wid  = threadIdx.x >> 6;
    const int gw   = blockIdx.x * 4 + wid;   // 0..32767
    const int b    = gw >> 12;               // 4096 waves / batch
    const int p0   = (gw & 4095) * 32;       // first point of this wave
    const int row  = lane & 15;              // point index within a 16-tile
    const int quad = lane >> 4;              // k-quad / D.row-quad

    __shared__ __align__(16) float smem[4][2048];    // 8 KB per wave
    float* ws = smem[wid];

    const size_t base = ((size_t)b * N_ + p0) * C_;
    const float* xb = x + base;
    float*       ob = out + base;

    // --- Stage both tiles (32 rows x 64 ch = 8 KB) linearly into LDS.
    #pragma unroll
    for (int t = 0; t < 2; ++t)
        #pragma unroll
        for (int c = 0; c < 4; ++c)
            __builtin_amdgcn_global_load_lds(
                (cglb_t*)(xb + t * 1024 + c * 256 + lane * 4),
                (lds_t*)(ws + t * 1024 + c * 256),
                16, 0, 0);

    // --- W fragments (L2-resident) + bias, overlapping the GLL latency.
    const short* wb = (const short*)(wmod) + b * 64 * 64;
    short8 wf00 = *(const short8*)(wb + ( 0 + row) * 64 +  0 + quad * 8);
    short8 wf01 = *(const short8*)(wb + ( 0 + row) * 64 + 32 + quad * 8);
    short8 wf10 = *(const short8*)(wb + (16 + row) * 64 +  0 + quad * 8);
    short8 wf11 = *(const short8*)(wb + (16 + row) * 64 + 32 + quad * 8);
    short8 wf20 = *(const short8*)(wb + (32 + row) * 64 +  0 + quad * 8);
    short8 wf21 = *(const short8*)(wb + (32 + row) * 64 + 32 + quad * 8);
    short8 wf30 = *(const short8*)(wb + (48 + row) * 64 +  0 + quad * 8);
    short8 wf31 = *(const short8*)(wb + (48 + row) * 64 + 32 + quad * 8);

    floatx4 bias_v0 = *(const floatx4*)(bias +  0 + quad * 4);
    floatx4 bias_v1 = *(const floatx4*)(bias + 16 + quad * 4);
    floatx4 bias_v2 = *(const floatx4*)(bias + 32 + quad * 4);
    floatx4 bias_v3 = *(const floatx4*)(bias + 48 + quad * 4);

    // Drain staging (and wf/bias) — per-wave, no barrier needed.
    asm volatile("s_waitcnt vmcnt(0)" ::: "memory");

    #pragma unroll
    for (int t = 0; t < 2; ++t) {
        float* wt = ws + t * 1024;

        // --- fragments from LDS: x[p=t*16+row][k = quad*8..+8, 32+quad*8..+8]
        const float* fr = wt + row * 64 + quad * 8;
        floatx4 a0 = *(const floatx4*)(fr);
        floatx4 a1 = *(const floatx4*)(fr + 4);
        floatx4 a2 = *(const floatx4*)(fr + 32);
        floatx4 a3 = *(const floatx4*)(fr + 36);

        short8 xf0, xf1;
        #pragma unroll
        for (int j = 0; j < 4; ++j) {
            xf0[j]     = bf16_of(a0[j]);
            xf0[j + 4] = bf16_of(a1[j]);
            xf1[j]     = bf16_of(a2[j]);
            xf1[j + 4] = bf16_of(a3[j]);
        }

        floatx4 acc0 = bias_v0, acc1 = bias_v1, acc2 = bias_v2, acc3 = bias_v3;
        acc0 = __builtin_amdgcn_mfma_f32_16x16x32_bf16(wf00, xf0, acc0, 0, 0, 0);
        acc0 = __builtin_amdgcn_mfma_f32_16x16x32_bf16(wf01, xf1, acc0, 0, 0, 0);
        acc1 = __builtin_amdgcn_mfma_f32_16x16x32_bf16(wf10, xf0, acc1, 0, 0, 0);
        acc1 = __builtin_amdgcn_mfma_f32_16x16x32_bf16(wf11, xf1, acc1, 0, 0, 0);
        acc2 = __builtin_amdgcn_mfma_f32_16x16x32_bf16(wf20, xf0, acc2, 0, 0, 0);
        acc2 = __builtin_amdgcn_mfma_f32_16x16x32_bf16(wf21, xf1, acc2, 0, 0, 0);
        acc3 = __builtin_amdgcn_mfma_f32_16x16x32_bf16(wf30, xf0, acc3, 0, 0, 0);
        acc3 = __builtin_amdgcn_mfma_f32_16x16x32_bf16(wf31, xf1, acc3, 0, 0, 0);

        // --- out-stage: scatter fragments into the consumed tile region.
        // D[m=out_ch][n=point]: lane holds channels mt*16+quad*4..+4 of
        // point (t*16+row) -> float idx row*64 + mt*16 + quad*4.
        float* wo = wt + row * 64 + quad * 4;
        *(floatx4*)(wo +  0) = acc0;
        *(floatx4*)(wo + 16) = acc1;
        *(floatx4*)(wo + 32) = acc2;
        *(floatx4*)(wo + 48) = acc3;

        // --- linear read-back + lane-contiguous global store (copy pattern)
        float* obt = ob + t * 1024;
        #pragma unroll
        for (int c = 0; c < 4; ++c) {
            floatx4 v = *(const floatx4*)(wt + c * 256 + lane * 4);
            *(floatx4*)(obt + c * 256 + lane * 4) = v;
        }
    }
}

extern "C" void kernel_launch(void* const* d_in, const int* in_sizes, int n_in,
                              void* d_out, int out_size, void* d_ws, size_t ws_size,
                              hipStream_t stream) {
    const float* x          = (const float*)d_in[0];
    const float* style      = (const float*)d_in[1];
    const float* weight     = (const float*)d_in[2];
    const float* bias       = (const float*)d_in[3];
    const float* mod_weight = (const float*)d_in[4];
    const float* mod_bias   = (const float*)d_in[5];
    float* out = (float*)d_out;
    __hip_bfloat16* wmod = (__hip_bfloat16*)d_ws;   // 8*64*64*2 = 64 KB

    modw_kernel<<<dim3(B_), dim3(256), 0, stream>>>(style, weight, mod_weight, mod_bias, wmod);
    conv_kernel<<<dim3((B_ * N_) / 128), dim3(256), 0, stream>>>(x, wmod, bias, out);
}